// Round 11
// baseline (981.495 us; speedup 1.0000x reference)
//
#include <hip/hip_runtime.h>
#include <hip/hip_fp16.h>

#define NROWS 4096
#define HID 64

typedef _Float16 h2_t __attribute__((ext_vector_type(2)));

static __device__ __forceinline__ __half2 u2h(unsigned u) {
  __half2 h; __builtin_memcpy(&h, &u, 4); return h;
}
static __device__ __forceinline__ unsigned h2u(__half2 h) {
  unsigned u; __builtin_memcpy(&u, &h, 4); return u;
}
static __device__ __forceinline__ h2_t u2hh(unsigned u) {
  h2_t h; __builtin_memcpy(&h, &u, 4); return h;
}

// ---------------- kernel 1: x=in@emb_w+b; q=x@q_w+b; khp=(x@k_w+b)^T fp16 --
// khp layout: dword (c>>1)*NROWS + col holds halves (c even, c odd).
__global__ __launch_bounds__(64) void k_embed(
    const float* __restrict__ inp, const float* __restrict__ emb_w,
    const float* __restrict__ emb_b, const float* __restrict__ q_w,
    const float* __restrict__ q_b, const float* __restrict__ k_w,
    const float* __restrict__ k_b, float* __restrict__ q,
    __half* __restrict__ khp, float* __restrict__ opk) {
  int row = blockIdx.x;
  int t = threadIdx.x;  // 64 threads; t = c
  __shared__ float in_s[8];
  __shared__ float x_s[64];
  if (t < 8) in_s[t] = inp[row * 8 + t];
  __syncthreads();
  float acc = emb_b[t];
#pragma unroll
  for (int i = 0; i < 8; ++i) acc += in_s[i] * emb_w[i * 64 + t];
  x_s[t] = acc;
  __syncthreads();
  float qa = q_b[t], ka = k_b[t];
#pragma unroll
  for (int i = 0; i < 64; ++i) {
    float xv = x_s[i];
    qa += xv * q_w[i * 64 + t];
    ka += xv * k_w[i * 64 + t];
  }
  q[row * 64 + t] = qa;
  khp[(size_t)(t >> 1) * 2 * NROWS + row * 2 + (t & 1)] = __float2half(ka);
  if (t < 4) opk[row * 4 + t] = inp[row * 8 + 4 + t];
}

// ---------------- kernel 2: scores via v_dot2_f32_f16 + in-reg softmax ----
// 512 blocks x 512 thr. Wave w owns row r0+w. Per 256-col tile: stage
// kls[32][256] dwords (c-pairs), double-buffered; per c2: 1 b128 read +
// 4 fdot2 (fp32 acc). One barrier per tile.
__global__ __launch_bounds__(512, 2) void k_scores(
    const float* __restrict__ q, const unsigned* __restrict__ khp,
    float* __restrict__ S) {
  __shared__ unsigned kls[2][32][256];  // 2 x 32 KB
  int t = threadIdx.x;
  int w = t >> 6;
  int g = t & 63;
  int row = blockIdx.x * 8 + w;
  unsigned qh[32];
  const float4* qp = (const float4*)(q + (size_t)row * 64);
#pragma unroll
  for (int i = 0; i < 16; ++i) {
    float4 v = qp[i];
    qh[2 * i] = h2u(__float22half2_rn(make_float2(v.x * 0.125f, v.y * 0.125f)));
    qh[2 * i + 1] = h2u(__float22half2_rn(make_float2(v.z * 0.125f, v.w * 0.125f)));
  }

#define STAGE(tile, b)                                                      \
  {                                                                         \
    _Pragma("unroll") for (int it = 0; it < 8; ++it) {                      \
      int n = it * 512 + t;                                                 \
      int c2 = n >> 7, j2 = n & 127;                                        \
      *(uint2*)&kls[b][c2][2 * j2] =                                        \
          *(const uint2*)(khp + (size_t)c2 * NROWS + (tile) * 256 + 2 * j2);\
    }                                                                       \
  }

  float4 sv[16];
  STAGE(0, 0);
#pragma unroll
  for (int tile = 0; tile < 16; ++tile) {
    __syncthreads();
    if (tile < 15) STAGE(tile + 1, (tile + 1) & 1);
    const unsigned(*kb)[256] = kls[tile & 1];
    float a0 = 0.f, a1 = 0.f, a2 = 0.f, a3 = 0.f;
#pragma unroll
    for (int c2 = 0; c2 < 32; ++c2) {
      uint4 kv = *(const uint4*)&kb[c2][g * 4];
      h2_t qv = u2hh(qh[c2]);
      a0 = __builtin_amdgcn_fdot2(u2hh(kv.x), qv, a0, false);
      a1 = __builtin_amdgcn_fdot2(u2hh(kv.y), qv, a1, false);
      a2 = __builtin_amdgcn_fdot2(u2hh(kv.z), qv, a2, false);
      a3 = __builtin_amdgcn_fdot2(u2hh(kv.w), qv, a3, false);
    }
    sv[tile] = make_float4(a0, a1, a2, a3);
  }
#undef STAGE
  float m = -1e30f;
#pragma unroll
  for (int tile = 0; tile < 16; ++tile) {
    float4 v = sv[tile];
    m = fmaxf(m, fmaxf(fmaxf(v.x, v.y), fmaxf(v.z, v.w)));
  }
#pragma unroll
  for (int off = 32; off > 0; off >>= 1) m = fmaxf(m, __shfl_xor(m, off, 64));
  float s = 0.f;
#pragma unroll
  for (int tile = 0; tile < 16; ++tile) {
    float4 v = sv[tile];
    v.x = __expf(v.x - m); v.y = __expf(v.y - m);
    v.z = __expf(v.z - m); v.w = __expf(v.w - m);
    sv[tile] = v;
    s += v.x + v.y + v.z + v.w;
  }
#pragma unroll
  for (int off = 32; off > 0; off >>= 1) s += __shfl_xor(s, off, 64);
  float li = 1.0f / s;
  float4* Sp = (float4*)(S + (size_t)row * NROWS);
#pragma unroll
  for (int tile = 0; tile < 16; ++tile) {
    float4 v = sv[tile];
    v.x *= li; v.y *= li; v.z *= li; v.w *= li;
    Sp[tile * 64 + g] = v;
  }
}

// ---------------- kernel 3: conv3 — packed fp16, 1 layer/pass, dbuf -------
#define SWH 128
#define SHH 50
#define SSTRH 130
#define OWW 236
#define OHH 30
#define GX 18
#define GY 137

__global__ __launch_bounds__(512, 2) void k_conv3(
    const float* __restrict__ attn, float* __restrict__ partial,
    const float* __restrict__ w1p, const float* __restrict__ w2p,
    const float* __restrict__ ap, const float* __restrict__ opk) {
  __shared__ unsigned buf[2][SHH * SSTRH];  // 2 x 26 KB
  int tid = threadIdx.x;
  int bx = blockIdx.x, by = blockIdx.y;
  int gi0 = by * OHH - 10;
  int gj0 = bx * OWW - 10;
  bool edge = (bx == 0) || (bx == GX - 1) || (by == 0) || (by == GY - 1);
  if (!edge) {
    for (int idx = tid; idx < SHH * SWH; idx += 512) {
      int r = idx >> 7, d = idx & 127;
      float2 v = *(const float2*)(attn + (size_t)(gi0 + r) * NROWS + gj0 + 2 * d);
      buf[0][r * SSTRH + d] =
          h2u(__float22half2_rn(make_float2(v.x * 256.f, v.y * 256.f)));
    }
  } else {
    for (int idx = tid; idx < SHH * SWH; idx += 512) {
      int r = idx >> 7, d = idx & 127;
      int gi = gi0 + r, gj = gj0 + 2 * d;
      float a = 0.f, b = 0.f;
      if ((unsigned)gi < (unsigned)NROWS) {
        if ((unsigned)gj < (unsigned)NROWS) a = attn[(size_t)gi * NROWS + gj] * 256.f;
        if ((unsigned)(gj + 1) < (unsigned)NROWS) b = attn[(size_t)gi * NROWS + gj + 1] * 256.f;
      }
      buf[0][r * SSTRH + d] = h2u(__float22half2_rn(make_float2(a, b)));
    }
  }
  __syncthreads();

  int wv = tid >> 6, l = tid & 63;
  int rb = 1 + 6 * wv;
  int doff = 2 * l;
  __half2 CM0 = __float2half2_rn(1.f), CM1 = __float2half2_rn(1.f);
  if (edge) {
    float m0 = ((unsigned)(gj0 + 4 * l + 0) < (unsigned)NROWS) ? 1.f : 0.f;
    float m1 = ((unsigned)(gj0 + 4 * l + 1) < (unsigned)NROWS) ? 1.f : 0.f;
    float m2 = ((unsigned)(gj0 + 4 * l + 2) < (unsigned)NROWS) ? 1.f : 0.f;
    float m3 = ((unsigned)(gj0 + 4 * l + 3) < (unsigned)NROWS) ? 1.f : 0.f;
    CM0 = __float22half2_rn(make_float2(m0, m1));
    CM1 = __float22half2_rn(make_float2(m2, m3));
  }

  for (int p = 0; p < 10; ++p) {
    unsigned* src = buf[p & 1];
    unsigned* dst = buf[(p + 1) & 1];
    __half2 W10 = __float2half2_rn(w1p[3 * p]);
    __half2 W12 = __float2half2_rn(w1p[3 * p + 2]);
    __half2 WC  = __float2half2_rn(w1p[3 * p + 1] + w2p[3 * p + 1]);
    __half2 W20 = __float2half2_rn(w2p[3 * p]);
    __half2 W22 = __float2half2_rn(w2p[3 * p + 2]);
    __half2 AL  = __float2half2_rn(ap[p]);
    uint2 Vm = *(uint2*)&src[(rb - 1) * SSTRH + doff];
    uint2 Vc = *(uint2*)&src[rb * SSTRH + doff];
#pragma unroll
    for (int s = 0; s < 6; ++s) {
      int r = rb + s;
      uint2 Vp = *(uint2*)&src[(r + 1) * SSTRH + doff];
      unsigned Lm1 = (unsigned)__builtin_amdgcn_update_dpp(
          0, (int)Vc.y, 0x138, 0xF, 0xF, true);  // wave_shr1
      unsigned Hp1 = (unsigned)__builtin_amdgcn_update_dpp(
          0, (int)Vc.x, 0x130, 0xF, 0xF, true);  // wave_shl1
      unsigned SL0 = __builtin_amdgcn_alignbit(Vc.x, Lm1, 16);
      unsigned SR0 = __builtin_amdgcn_alignbit(Vc.y, Vc.x, 16);
      unsigned SR1 = __builtin_amdgcn_alignbit(Hp1, Vc.y, 16);
      __half2 o0 = __hmul2(WC, u2h(Vc.x));
      o0 = __hfma2(W10, u2h(SL0), o0);
      o0 = __hfma2(W12, u2h(SR0), o0);
      o0 = __hfma2(W20, u2h(Vm.x), o0);
      o0 = __hfma2(W22, u2h(Vp.x), o0);
      __half2 o1 = __hmul2(WC, u2h(Vc.y));
      o1 = __hfma2(W10, u2h(SR0), o1);
      o1 = __hfma2(W12, u2h(SR1), o1);
      o1 = __hfma2(W20, u2h(Vm.y), o1);
      o1 = __hfma2(W22, u2h(Vp.y), o1);
      // leaky relu = max(x, a*x) for 0<a<1, via v_pk_max_f16
      {
        unsigned u0 = h2u(o0), ua0 = h2u(__hmul2(AL, o0)), r0;
        asm("v_pk_max_f16 %0, %1, %2" : "=v"(r0) : "v"(u0), "v"(ua0));
        o0 = u2h(r0);
        unsigned u1 = h2u(o1), ua1 = h2u(__hmul2(AL, o1)), r1;
        asm("v_pk_max_f16 %0, %1, %2" : "=v"(r1) : "v"(u1), "v"(ua1));
        o1 = u2h(r1);
      }
      if (edge) {
        o0 = __hmul2(o0, CM0);
        o1 = __hmul2(o1, CM1);
        if ((unsigned)(gi0 + r) >= (unsigned)NROWS) {
          o0 = __float2half2_rn(0.f);
          o1 = __float2half2_rn(0.f);
        }
      }
      uint2 res = {h2u(o0), h2u(o1)};
      *(uint2*)&dst[r * SSTRH + doff] = res;
      Vm = Vc; Vc = Vp;
    }
    __syncthreads();
  }

  // ---- epilogue: masked dot over interior rows [10,40), cols [10,246) ----
  const unsigned* fin = buf[0];
  int i = tid >> 4;
  int part = tid & 15;
  int gi = gi0 + 10 + i;
  float a0 = 0.f, a1 = 0.f, a2 = 0.f, a3 = 0.f;
  if (i < OHH && gi < NROWS) {
    for (int g = part; g < 59; g += 16) {
      int jc = 10 + 4 * g;
      int gj = gj0 + jc;
      if (gj + 3 < NROWS) {
        unsigned d0 = fin[(10 + i) * SSTRH + (jc >> 1)];
        unsigned d1 = fin[(10 + i) * SSTRH + (jc >> 1) + 1];
        __half2 h0 = u2h(d0), h1 = u2h(d1);
        float4 av = *(const float4*)(attn + (size_t)gi * NROWS + gj);
        const float4* op = (const float4*)opk;
        if (__low2float(h0) > 0.f)  { float4 o = op[gj + 0]; a0 += av.x * o.x; a1 += av.x * o.y; a2 += av.x * o.z; a3 += av.x * o.w; }
        if (__high2float(h0) > 0.f) { float4 o = op[gj + 1]; a0 += av.y * o.x; a1 += av.y * o.y; a2 += av.y * o.z; a3 += av.y * o.w; }
        if (__low2float(h1) > 0.f)  { float4 o = op[gj + 2]; a0 += av.z * o.x; a1 += av.z * o.y; a2 += av.z * o.z; a3 += av.z * o.w; }
        if (__high2float(h1) > 0.f) { float4 o = op[gj + 3]; a0 += av.w * o.x; a1 += av.w * o.y; a2 += av.w * o.z; a3 += av.w * o.w; }
      }
    }
  }
#pragma unroll
  for (int off = 1; off < 16; off <<= 1) {
    a0 += __shfl_xor(a0, off, 64);
    a1 += __shfl_xor(a1, off, 64);
    a2 += __shfl_xor(a2, off, 64);
    a3 += __shfl_xor(a3, off, 64);
  }
  if (part == 0 && i < OHH && gi < NROWS) {
    float4 r = {a0, a1, a2, a3};
    *(float4*)&partial[((size_t)bx * NROWS + gi) * 4] = r;
  }
}

// ---------------- kernel 4: reduce 18 partials + gcn + mlp head -----------
__global__ __launch_bounds__(64) void k_head(
    const float* __restrict__ partial, const float* __restrict__ gcn_w,
    const float* __restrict__ gcn_b, const float* __restrict__ gcn_a,
    const float* __restrict__ w1, const float* __restrict__ b1,
    const float* __restrict__ w2, const float* __restrict__ b2,
    float* __restrict__ out) {
  int row = blockIdx.x;
  int t = threadIdx.x;  // 64
  __shared__ float c4[4];
  __shared__ float gs[64];
  __shared__ float ms[32];
  {
    int c = t & 3, gg = t >> 2;
    float s = partial[((size_t)gg * NROWS + row) * 4 + c];
    if (gg < GX - 16)
      s += partial[((size_t)(gg + 16) * NROWS + row) * 4 + c];
#pragma unroll
    for (int off = 4; off < 64; off <<= 1) s += __shfl_xor(s, off, 64);
    if (t < 4) c4[t] = s;
  }
  __syncthreads();
  float g = gcn_b[t];
#pragma unroll
  for (int d = 0; d < 4; ++d) g += c4[d] * gcn_w[d * 64 + t];
  float ga = gcn_a[0];
  gs[t] = (g >= 0.f) ? g : ga * g;
  __syncthreads();
  if (t < 32) {
    float mm = b1[t];
#pragma unroll
    for (int i = 0; i < 64; ++i) mm += gs[i] * w1[i * 32 + t];
    ms[t] = fmaxf(mm, 0.f);
  }
  __syncthreads();
  if (t < 4) {
    float o = b2[t];
#pragma unroll
    for (int i = 0; i < 32; ++i) o += ms[i] * w2[i * 4 + t];
    out[row * 4 + t] = o;
  }
}

extern "C" void kernel_launch(void* const* d_in, const int* in_sizes, int n_in,
                              void* d_out, int out_size, void* d_ws, size_t ws_size,
                              hipStream_t stream) {
  (void)in_sizes; (void)n_in; (void)out_size; (void)ws_size;
  const float* inp    = (const float*)d_in[0];
  const float* emb_w  = (const float*)d_in[1];
  const float* emb_b  = (const float*)d_in[2];
  const float* q_w    = (const float*)d_in[3];
  const float* q_b    = (const float*)d_in[4];
  const float* k_w    = (const float*)d_in[5];
  const float* k_b    = (const float*)d_in[6];
  const float* conv_w1 = (const float*)d_in[7];
  const float* conv_w2 = (const float*)d_in[8];
  const float* conv_a  = (const float*)d_in[9];
  const float* gcn_w  = (const float*)d_in[10];
  const float* gcn_b  = (const float*)d_in[11];
  const float* gcn_a  = (const float*)d_in[12];
  const float* mlp_w1 = (const float*)d_in[13];
  const float* mlp_b1 = (const float*)d_in[14];
  const float* mlp_w2 = (const float*)d_in[15];
  const float* mlp_b2 = (const float*)d_in[16];
  float* out = (float*)d_out;

  const size_t NN = (size_t)NROWS * NROWS;
  float* A       = (float*)d_ws;                      // 4096^2 attn
  float* partial = A + NN;                            // GX * 4096 * 4
  float* q       = partial + (size_t)GX * NROWS * 4;
  float* khp     = q + (size_t)NROWS * HID;           // 4096*64 fp16 = 128K floats
  float* opk     = khp + (size_t)NROWS * HID / 2;

  k_embed<<<NROWS, 64, 0, stream>>>(inp, emb_w, emb_b, q_w, q_b, k_w, k_b, q,
                                    (__half*)khp, opk);
  k_scores<<<NROWS / 8, 512, 0, stream>>>(q, (const unsigned*)khp, A);
  k_conv3<<<dim3(GX, GY), 512, 0, stream>>>(A, partial, conv_w1, conv_w2,
                                            conv_a, opk);
  k_head<<<NROWS, 64, 0, stream>>>(partial, gcn_w, gcn_b, gcn_a, mlp_w1, mlp_b1,
                                   mlp_w2, mlp_b2, out);
}

// Round 12
// 236.186 us; speedup vs baseline: 4.1556x; 4.1556x over previous
//
#include <hip/hip_runtime.h>
#include <hip/hip_fp16.h>

#define NROWS 4096
#define HID 64

typedef _Float16 h2_t __attribute__((ext_vector_type(2)));

static __device__ __forceinline__ __half2 u2h(unsigned u) {
  __half2 h; __builtin_memcpy(&h, &u, 4); return h;
}
static __device__ __forceinline__ unsigned h2u(__half2 h) {
  unsigned u; __builtin_memcpy(&u, &h, 4); return u;
}
static __device__ __forceinline__ h2_t u2hh(unsigned u) {
  h2_t h; __builtin_memcpy(&h, &u, 4); return h;
}

// ---------------- kernel 1: x=in@emb_w+b; q=x@q_w+b; khp=(x@k_w+b)^T fp16 --
// khp dword layout: dword (c>>1)*NROWS + col = halves (k[c_even], k[c_odd]).
__global__ __launch_bounds__(64) void k_embed(
    const float* __restrict__ inp, const float* __restrict__ emb_w,
    const float* __restrict__ emb_b, const float* __restrict__ q_w,
    const float* __restrict__ q_b, const float* __restrict__ k_w,
    const float* __restrict__ k_b, float* __restrict__ q,
    __half* __restrict__ khp, float* __restrict__ opk) {
  int row = blockIdx.x;
  int t = threadIdx.x;  // 64 threads; t = c
  __shared__ float in_s[8];
  __shared__ float x_s[64];
  if (t < 8) in_s[t] = inp[row * 8 + t];
  __syncthreads();
  float acc = emb_b[t];
#pragma unroll
  for (int i = 0; i < 8; ++i) acc += in_s[i] * emb_w[i * 64 + t];
  x_s[t] = acc;
  __syncthreads();
  float qa = q_b[t], ka = k_b[t];
#pragma unroll
  for (int i = 0; i < 64; ++i) {
    float xv = x_s[i];
    qa += xv * q_w[i * 64 + t];
    ka += xv * k_w[i * 64 + t];
  }
  q[row * 64 + t] = qa;
  khp[(size_t)(t >> 1) * 2 * NROWS + row * 2 + (t & 1)] = __float2half(ka);
  if (t < 4) opk[row * 4 + t] = inp[row * 8 + 4 + t];
}

// ---------------- kernel 2: scores via fdot2, HALF-ROW per wave -----------
// 1024 blocks x 512 thr. Wave w: row blockIdx*4 + (w>>1), half h = w&1
// (cols [h*2048, h*2048+2048)). sv[8] (32 VGPR) + qh[32] -> no spill.
// Per 256-col tile: stage kls[32][512] (both halves' chunks); fdot2 compute;
// cross-half (m,l) via tiny LDS exchange; attn written once.
__global__ __launch_bounds__(512, 2) void k_scores(
    const float* __restrict__ q, const unsigned* __restrict__ khp,
    float* __restrict__ S) {
  __shared__ unsigned kls[32][512];  // 64 KB
  __shared__ float red[4][2];
  int t = threadIdx.x;
  int w = t >> 6;
  int g = t & 63;
  int rloc = w >> 1;
  int h = w & 1;
  int row = blockIdx.x * 4 + rloc;
  unsigned qh[32];
  const float4* qp = (const float4*)(q + (size_t)row * 64);
#pragma unroll
  for (int i = 0; i < 16; ++i) {
    float4 v = qp[i];
    qh[2 * i] = h2u(__float22half2_rn(make_float2(v.x * 0.125f, v.y * 0.125f)));
    qh[2 * i + 1] = h2u(__float22half2_rn(make_float2(v.z * 0.125f, v.w * 0.125f)));
  }
  float4 sv[8];
#pragma unroll 1
  for (int tile = 0; tile < 8; ++tile) {
    __syncthreads();
#pragma unroll
    for (int it = 0; it < 16; ++it) {
      int n = it * 512 + t;
      int c2 = n >> 8;   // 0..31
      int j2 = n & 255;  // uint2 slot in 512-dword row
      int col = (j2 < 128) ? (tile * 256 + 2 * j2)
                           : (2048 + tile * 256 + 2 * (j2 - 128));
      *(uint2*)&kls[c2][2 * j2] = *(const uint2*)(khp + (size_t)c2 * NROWS + col);
    }
    __syncthreads();
    float a0 = 0.f, a1 = 0.f, a2 = 0.f, a3 = 0.f;
    int off = h * 256 + g * 4;
#pragma unroll
    for (int c2 = 0; c2 < 32; ++c2) {
      uint4 kv = *(const uint4*)&kls[c2][off];
      h2_t qv = u2hh(qh[c2]);
      a0 = __builtin_amdgcn_fdot2(u2hh(kv.x), qv, a0, false);
      a1 = __builtin_amdgcn_fdot2(u2hh(kv.y), qv, a1, false);
      a2 = __builtin_amdgcn_fdot2(u2hh(kv.z), qv, a2, false);
      a3 = __builtin_amdgcn_fdot2(u2hh(kv.w), qv, a3, false);
    }
    sv[tile] = make_float4(a0, a1, a2, a3);
  }
  // half-row max
  float m = -1e30f;
#pragma unroll
  for (int tile = 0; tile < 8; ++tile) {
    float4 v = sv[tile];
    m = fmaxf(m, fmaxf(fmaxf(v.x, v.y), fmaxf(v.z, v.w)));
  }
#pragma unroll
  for (int off = 32; off > 0; off >>= 1) m = fmaxf(m, __shfl_xor(m, off, 64));
  if (g == 0) red[rloc][h] = m;
  __syncthreads();
  m = fmaxf(red[rloc][0], red[rloc][1]);
  __syncthreads();  // all reads of max done before sum overwrites
  // exp + half sum
  float s = 0.f;
#pragma unroll
  for (int tile = 0; tile < 8; ++tile) {
    float4 v = sv[tile];
    v.x = __expf(v.x - m); v.y = __expf(v.y - m);
    v.z = __expf(v.z - m); v.w = __expf(v.w - m);
    sv[tile] = v;
    s += v.x + v.y + v.z + v.w;
  }
#pragma unroll
  for (int off = 32; off > 0; off >>= 1) s += __shfl_xor(s, off, 64);
  if (g == 0) red[rloc][h] = s;
  __syncthreads();
  float li = 1.0f / (red[rloc][0] + red[rloc][1]);
  float4* Sp = (float4*)(S + (size_t)row * NROWS + h * 2048);
#pragma unroll
  for (int tile = 0; tile < 8; ++tile) {
    float4 v = sv[tile];
    v.x *= li; v.y *= li; v.z *= li; v.w *= li;
    Sp[tile * 64 + g] = v;
  }
}

// ---------------- kernel 3: conv3 — packed fp16, 1 layer/pass, dbuf -------
#define SWH 128
#define SHH 50
#define SSTRH 130
#define OWW 236
#define OHH 30
#define GX 18
#define GY 137

__global__ __launch_bounds__(512, 2) void k_conv3(
    const float* __restrict__ attn, float* __restrict__ partial,
    const float* __restrict__ w1p, const float* __restrict__ w2p,
    const float* __restrict__ ap, const float* __restrict__ opk) {
  __shared__ unsigned buf[2][SHH * SSTRH];  // 2 x 26 KB
  int tid = threadIdx.x;
  int bx = blockIdx.x, by = blockIdx.y;
  int gi0 = by * OHH - 10;
  int gj0 = bx * OWW - 10;
  bool edge = (bx == 0) || (bx == GX - 1) || (by == 0) || (by == GY - 1);
  if (!edge) {
    for (int idx = tid; idx < SHH * SWH; idx += 512) {
      int r = idx >> 7, d = idx & 127;
      float2 v = *(const float2*)(attn + (size_t)(gi0 + r) * NROWS + gj0 + 2 * d);
      buf[0][r * SSTRH + d] =
          h2u(__float22half2_rn(make_float2(v.x * 256.f, v.y * 256.f)));
    }
  } else {
    for (int idx = tid; idx < SHH * SWH; idx += 512) {
      int r = idx >> 7, d = idx & 127;
      int gi = gi0 + r, gj = gj0 + 2 * d;
      float a = 0.f, b = 0.f;
      if ((unsigned)gi < (unsigned)NROWS) {
        if ((unsigned)gj < (unsigned)NROWS) a = attn[(size_t)gi * NROWS + gj] * 256.f;
        if ((unsigned)(gj + 1) < (unsigned)NROWS) b = attn[(size_t)gi * NROWS + gj + 1] * 256.f;
      }
      buf[0][r * SSTRH + d] = h2u(__float22half2_rn(make_float2(a, b)));
    }
  }
  __syncthreads();

  int wv = tid >> 6, l = tid & 63;
  int rb = 1 + 6 * wv;
  int doff = 2 * l;
  __half2 CM0 = __float2half2_rn(1.f), CM1 = __float2half2_rn(1.f);
  if (edge) {
    float m0 = ((unsigned)(gj0 + 4 * l + 0) < (unsigned)NROWS) ? 1.f : 0.f;
    float m1 = ((unsigned)(gj0 + 4 * l + 1) < (unsigned)NROWS) ? 1.f : 0.f;
    float m2 = ((unsigned)(gj0 + 4 * l + 2) < (unsigned)NROWS) ? 1.f : 0.f;
    float m3 = ((unsigned)(gj0 + 4 * l + 3) < (unsigned)NROWS) ? 1.f : 0.f;
    CM0 = __float22half2_rn(make_float2(m0, m1));
    CM1 = __float22half2_rn(make_float2(m2, m3));
  }

  for (int p = 0; p < 10; ++p) {
    unsigned* src = buf[p & 1];
    unsigned* dst = buf[(p + 1) & 1];
    __half2 W10 = __float2half2_rn(w1p[3 * p]);
    __half2 W12 = __float2half2_rn(w1p[3 * p + 2]);
    __half2 WC  = __float2half2_rn(w1p[3 * p + 1] + w2p[3 * p + 1]);
    __half2 W20 = __float2half2_rn(w2p[3 * p]);
    __half2 W22 = __float2half2_rn(w2p[3 * p + 2]);
    __half2 AL  = __float2half2_rn(ap[p]);
    uint2 Vm = *(uint2*)&src[(rb - 1) * SSTRH + doff];
    uint2 Vc = *(uint2*)&src[rb * SSTRH + doff];
#pragma unroll
    for (int s = 0; s < 6; ++s) {
      int r = rb + s;
      uint2 Vp = *(uint2*)&src[(r + 1) * SSTRH + doff];
      unsigned Lm1 = (unsigned)__builtin_amdgcn_update_dpp(
          0, (int)Vc.y, 0x138, 0xF, 0xF, true);  // wave_shr1
      unsigned Hp1 = (unsigned)__builtin_amdgcn_update_dpp(
          0, (int)Vc.x, 0x130, 0xF, 0xF, true);  // wave_shl1
      unsigned SL0 = __builtin_amdgcn_alignbit(Vc.x, Lm1, 16);
      unsigned SR0 = __builtin_amdgcn_alignbit(Vc.y, Vc.x, 16);
      unsigned SR1 = __builtin_amdgcn_alignbit(Hp1, Vc.y, 16);
      __half2 o0 = __hmul2(WC, u2h(Vc.x));
      o0 = __hfma2(W10, u2h(SL0), o0);
      o0 = __hfma2(W12, u2h(SR0), o0);
      o0 = __hfma2(W20, u2h(Vm.x), o0);
      o0 = __hfma2(W22, u2h(Vp.x), o0);
      __half2 o1 = __hmul2(WC, u2h(Vc.y));
      o1 = __hfma2(W10, u2h(SR0), o1);
      o1 = __hfma2(W12, u2h(SR1), o1);
      o1 = __hfma2(W20, u2h(Vm.y), o1);
      o1 = __hfma2(W22, u2h(Vp.y), o1);
      // leaky relu = max(x, a*x), 0<a<1, via v_pk_max_f16
      {
        unsigned u0 = h2u(o0), ua0 = h2u(__hmul2(AL, o0)), r0;
        asm("v_pk_max_f16 %0, %1, %2" : "=v"(r0) : "v"(u0), "v"(ua0));
        o0 = u2h(r0);
        unsigned u1 = h2u(o1), ua1 = h2u(__hmul2(AL, o1)), r1;
        asm("v_pk_max_f16 %0, %1, %2" : "=v"(r1) : "v"(u1), "v"(ua1));
        o1 = u2h(r1);
      }
      if (edge) {
        o0 = __hmul2(o0, CM0);
        o1 = __hmul2(o1, CM1);
        if ((unsigned)(gi0 + r) >= (unsigned)NROWS) {
          o0 = __float2half2_rn(0.f);
          o1 = __float2half2_rn(0.f);
        }
      }
      uint2 res = {h2u(o0), h2u(o1)};
      *(uint2*)&dst[r * SSTRH + doff] = res;
      Vm = Vc; Vc = Vp;
    }
    __syncthreads();
  }

  // ---- epilogue: masked dot over interior rows [10,40), cols [10,246) ----
  const unsigned* fin = buf[0];
  int i = tid >> 4;
  int part = tid & 15;
  int gi = gi0 + 10 + i;
  float a0 = 0.f, a1 = 0.f, a2 = 0.f, a3 = 0.f;
  if (i < OHH && gi < NROWS) {
    for (int g = part; g < 59; g += 16) {
      int jc = 10 + 4 * g;
      int gj = gj0 + jc;
      if (gj + 3 < NROWS) {
        unsigned d0 = fin[(10 + i) * SSTRH + (jc >> 1)];
        unsigned d1 = fin[(10 + i) * SSTRH + (jc >> 1) + 1];
        __half2 h0 = u2h(d0), h1 = u2h(d1);
        float4 av = *(const float4*)(attn + (size_t)gi * NROWS + gj);
        const float4* op = (const float4*)opk;
        if (__low2float(h0) > 0.f)  { float4 o = op[gj + 0]; a0 += av.x * o.x; a1 += av.x * o.y; a2 += av.x * o.z; a3 += av.x * o.w; }
        if (__high2float(h0) > 0.f) { float4 o = op[gj + 1]; a0 += av.y * o.x; a1 += av.y * o.y; a2 += av.y * o.z; a3 += av.y * o.w; }
        if (__low2float(h1) > 0.f)  { float4 o = op[gj + 2]; a0 += av.z * o.x; a1 += av.z * o.y; a2 += av.z * o.z; a3 += av.z * o.w; }
        if (__high2float(h1) > 0.f) { float4 o = op[gj + 3]; a0 += av.w * o.x; a1 += av.w * o.y; a2 += av.w * o.z; a3 += av.w * o.w; }
      }
    }
  }
#pragma unroll
  for (int off = 1; off < 16; off <<= 1) {
    a0 += __shfl_xor(a0, off, 64);
    a1 += __shfl_xor(a1, off, 64);
    a2 += __shfl_xor(a2, off, 64);
    a3 += __shfl_xor(a3, off, 64);
  }
  if (part == 0 && i < OHH && gi < NROWS) {
    float4 r = {a0, a1, a2, a3};
    *(float4*)&partial[((size_t)bx * NROWS + gi) * 4] = r;
  }
}

// ---------------- kernel 4: reduce 18 partials + gcn + mlp head -----------
__global__ __launch_bounds__(64) void k_head(
    const float* __restrict__ partial, const float* __restrict__ gcn_w,
    const float* __restrict__ gcn_b, const float* __restrict__ gcn_a,
    const float* __restrict__ w1, const float* __restrict__ b1,
    const float* __restrict__ w2, const float* __restrict__ b2,
    float* __restrict__ out) {
  int row = blockIdx.x;
  int t = threadIdx.x;  // 64
  __shared__ float c4[4];
  __shared__ float gs[64];
  __shared__ float ms[32];
  {
    int c = t & 3, gg = t >> 2;
    float s = partial[((size_t)gg * NROWS + row) * 4 + c];
    if (gg < GX - 16)
      s += partial[((size_t)(gg + 16) * NROWS + row) * 4 + c];
#pragma unroll
    for (int off = 4; off < 64; off <<= 1) s += __shfl_xor(s, off, 64);
    if (t < 4) c4[t] = s;
  }
  __syncthreads();
  float g = gcn_b[t];
#pragma unroll
  for (int d = 0; d < 4; ++d) g += c4[d] * gcn_w[d * 64 + t];
  float ga = gcn_a[0];
  gs[t] = (g >= 0.f) ? g : ga * g;
  __syncthreads();
  if (t < 32) {
    float mm = b1[t];
#pragma unroll
    for (int i = 0; i < 64; ++i) mm += gs[i] * w1[i * 32 + t];
    ms[t] = fmaxf(mm, 0.f);
  }
  __syncthreads();
  if (t < 4) {
    float o = b2[t];
#pragma unroll
    for (int i = 0; i < 32; ++i) o += ms[i] * w2[i * 4 + t];
    out[row * 4 + t] = o;
  }
}

extern "C" void kernel_launch(void* const* d_in, const int* in_sizes, int n_in,
                              void* d_out, int out_size, void* d_ws, size_t ws_size,
                              hipStream_t stream) {
  (void)in_sizes; (void)n_in; (void)out_size; (void)ws_size;
  const float* inp    = (const float*)d_in[0];
  const float* emb_w  = (const float*)d_in[1];
  const float* emb_b  = (const float*)d_in[2];
  const float* q_w    = (const float*)d_in[3];
  const float* q_b    = (const float*)d_in[4];
  const float* k_w    = (const float*)d_in[5];
  const float* k_b    = (const float*)d_in[6];
  const float* conv_w1 = (const float*)d_in[7];
  const float* conv_w2 = (const float*)d_in[8];
  const float* conv_a  = (const float*)d_in[9];
  const float* gcn_w  = (const float*)d_in[10];
  const float* gcn_b  = (const float*)d_in[11];
  const float* gcn_a  = (const float*)d_in[12];
  const float* mlp_w1 = (const float*)d_in[13];
  const float* mlp_b1 = (const float*)d_in[14];
  const float* mlp_w2 = (const float*)d_in[15];
  const float* mlp_b2 = (const float*)d_in[16];
  float* out = (float*)d_out;

  const size_t NN = (size_t)NROWS * NROWS;
  float* A       = (float*)d_ws;                      // 4096^2 attn
  float* partial = A + NN;                            // GX * 4096 * 4
  float* q       = partial + (size_t)GX * NROWS * 4;
  float* khp     = q + (size_t)NROWS * HID;           // fp16 kT, 512 KB
  float* opk     = khp + (size_t)NROWS * HID / 2;

  k_embed<<<NROWS, 64, 0, stream>>>(inp, emb_w, emb_b, q_w, q_b, k_w, k_b, q,
                                    (__half*)khp, opk);
  k_scores<<<NROWS / 4, 512, 0, stream>>>(q, (const unsigned*)khp, A);
  k_conv3<<<dim3(GX, GY), 512, 0, stream>>>(A, partial, conv_w1, conv_w2,
                                            conv_a, opk);
  k_head<<<NROWS, 64, 0, stream>>>(partial, gcn_w, gcn_b, gcn_a, mlp_w1, mlp_b1,
                                   mlp_w2, mlp_b2, out);
}

// Round 13
// 129.033 us; speedup vs baseline: 7.6066x; 1.8304x over previous
//
#include <hip/hip_runtime.h>
#include <hip/hip_fp16.h>

#define NROWS 4096
#define HID 64

typedef _Float16 f16x8 __attribute__((ext_vector_type(8)));
typedef float f32x4 __attribute__((ext_vector_type(4)));

static __device__ __forceinline__ __half2 u2h(unsigned u) {
  __half2 h; __builtin_memcpy(&h, &u, 4); return h;
}
static __device__ __forceinline__ unsigned h2u(__half2 h) {
  unsigned u; __builtin_memcpy(&u, &h, 4); return u;
}

// ---------------- kernel 1: x=in@emb_w+b; qh=(x@q_w+b)*0.125 fp16;
//                  kh=(x@k_w+b) fp16 row-major; opk pack -----------------
__global__ __launch_bounds__(64) void k_embed(
    const float* __restrict__ inp, const float* __restrict__ emb_w,
    const float* __restrict__ emb_b, const float* __restrict__ q_w,
    const float* __restrict__ q_b, const float* __restrict__ k_w,
    const float* __restrict__ k_b, __half* __restrict__ qh,
    __half* __restrict__ kh, float* __restrict__ opk) {
  int row = blockIdx.x;
  int t = threadIdx.x;  // 64 threads
  __shared__ float in_s[8];
  __shared__ float x_s[64];
  if (t < 8) in_s[t] = inp[row * 8 + t];
  __syncthreads();
  float acc = emb_b[t];
#pragma unroll
  for (int i = 0; i < 8; ++i) acc += in_s[i] * emb_w[i * 64 + t];
  x_s[t] = acc;
  __syncthreads();
  float qa = q_b[t], ka = k_b[t];
#pragma unroll
  for (int i = 0; i < 64; ++i) {
    float xv = x_s[i];
    qa += xv * q_w[i * 64 + t];
    ka += xv * k_w[i * 64 + t];
  }
  qh[row * 64 + t] = __float2half(qa * 0.125f);  // fold 1/sqrt(64)
  kh[row * 64 + t] = __float2half(ka);
  if (t < 4) opk[row * 4 + t] = inp[row * 8 + 4 + t];
}

// ---------------- kernel 2: MFMA scores + softmax -------------------------
// 256 blocks x 512 thr (8 waves). Block owns rows [blockIdx*16, +16);
// wave w owns 32 col-tiles of 16. mfma_f32_16x16x32_f16, K=64 in 2 steps.
// A-frag: 8 contiguous halves of Q row (lane&15) at (lane>>4)*8 (+32 for s1);
// B-frag: SAME pattern on K rows -> layout-permutation cancels.
// C layout (verified): col=lane&15, row=(lane>>4)*4+comp.
__global__ __launch_bounds__(512, 2) void k_scores(
    const __half* __restrict__ qh, const __half* __restrict__ kh,
    float* __restrict__ S) {
  __shared__ float redm[8][16];
  __shared__ float reds[8][16];
  int t = threadIdx.x;
  int w = t >> 6;
  int l = t & 63;
  int m16 = l & 15;
  int g4 = l >> 4;
  int rb = blockIdx.x * 16;
  const uint4* qq = (const uint4*)qh;  // row = 8 uint4 (64 halves)
  const uint4* kk = (const uint4*)kh;
  int qrow = rb + m16;
  f16x8 a0 = __builtin_bit_cast(f16x8, qq[qrow * 8 + g4]);      // k 0..31
  f16x8 a1 = __builtin_bit_cast(f16x8, qq[qrow * 8 + 4 + g4]);  // k 32..63
  f32x4 acc[32];
#pragma unroll
  for (int i = 0; i < 32; ++i) acc[i] = (f32x4){0.f, 0.f, 0.f, 0.f};
#pragma unroll
  for (int i = 0; i < 32; ++i) {
    int kcol = (w * 32 + i) * 16 + m16;
    f16x8 b0 = __builtin_bit_cast(f16x8, kk[kcol * 8 + g4]);
    f16x8 b1 = __builtin_bit_cast(f16x8, kk[kcol * 8 + 4 + g4]);
    acc[i] = __builtin_amdgcn_mfma_f32_16x16x32_f16(a0, b0, acc[i], 0, 0, 0);
    acc[i] = __builtin_amdgcn_mfma_f32_16x16x32_f16(a1, b1, acc[i], 0, 0, 0);
  }
  // per-row max: in-reg over tiles, shfl over the 16-lane col group
  float m4[4] = {-1e30f, -1e30f, -1e30f, -1e30f};
#pragma unroll
  for (int i = 0; i < 32; ++i) {
#pragma unroll
    for (int c = 0; c < 4; ++c) m4[c] = fmaxf(m4[c], acc[i][c]);
  }
#pragma unroll
  for (int off = 1; off < 16; off <<= 1) {
#pragma unroll
    for (int c = 0; c < 4; ++c) m4[c] = fmaxf(m4[c], __shfl_xor(m4[c], off, 64));
  }
  if (m16 == 0) {
#pragma unroll
    for (int c = 0; c < 4; ++c) redm[w][g4 * 4 + c] = m4[c];
  }
  __syncthreads();
#pragma unroll
  for (int c = 0; c < 4; ++c) {
    float mm = redm[0][g4 * 4 + c];
#pragma unroll
    for (int ww = 1; ww < 8; ++ww) mm = fmaxf(mm, redm[ww][g4 * 4 + c]);
    m4[c] = mm;
  }
  // exp + per-row sum
  float s4[4] = {0.f, 0.f, 0.f, 0.f};
#pragma unroll
  for (int i = 0; i < 32; ++i) {
#pragma unroll
    for (int c = 0; c < 4; ++c) {
      float e = __expf(acc[i][c] - m4[c]);
      acc[i][c] = e;
      s4[c] += e;
    }
  }
#pragma unroll
  for (int off = 1; off < 16; off <<= 1) {
#pragma unroll
    for (int c = 0; c < 4; ++c) s4[c] += __shfl_xor(s4[c], off, 64);
  }
  if (m16 == 0) {
#pragma unroll
    for (int c = 0; c < 4; ++c) reds[w][g4 * 4 + c] = s4[c];
  }
  __syncthreads();
  float li[4];
#pragma unroll
  for (int c = 0; c < 4; ++c) {
    float ss = reds[0][g4 * 4 + c];
#pragma unroll
    for (int ww = 1; ww < 8; ++ww) ss += reds[ww][g4 * 4 + c];
    li[c] = 1.0f / ss;
  }
  // scaled store
#pragma unroll
  for (int i = 0; i < 32; ++i) {
    int col = (w * 32 + i) * 16 + m16;
#pragma unroll
    for (int c = 0; c < 4; ++c) {
      S[(size_t)(rb + g4 * 4 + c) * NROWS + col] = acc[i][c] * li[c];
    }
  }
}

// ---------------- kernel 3: conv3 — packed fp16, 1 layer/pass, dbuf -------
#define SWH 128
#define SHH 50
#define SSTRH 130
#define OWW 236
#define OHH 30
#define GX 18
#define GY 137

__global__ __launch_bounds__(512, 2) void k_conv3(
    const float* __restrict__ attn, float* __restrict__ partial,
    const float* __restrict__ w1p, const float* __restrict__ w2p,
    const float* __restrict__ ap, const float* __restrict__ opk) {
  __shared__ unsigned buf[2][SHH * SSTRH];  // 2 x 26 KB
  int tid = threadIdx.x;
  int bx = blockIdx.x, by = blockIdx.y;
  int gi0 = by * OHH - 10;
  int gj0 = bx * OWW - 10;
  bool edge = (bx == 0) || (bx == GX - 1) || (by == 0) || (by == GY - 1);
  if (!edge) {
    for (int idx = tid; idx < SHH * SWH; idx += 512) {
      int r = idx >> 7, d = idx & 127;
      float2 v = *(const float2*)(attn + (size_t)(gi0 + r) * NROWS + gj0 + 2 * d);
      buf[0][r * SSTRH + d] =
          h2u(__float22half2_rn(make_float2(v.x * 256.f, v.y * 256.f)));
    }
  } else {
    for (int idx = tid; idx < SHH * SWH; idx += 512) {
      int r = idx >> 7, d = idx & 127;
      int gi = gi0 + r, gj = gj0 + 2 * d;
      float a = 0.f, b = 0.f;
      if ((unsigned)gi < (unsigned)NROWS) {
        if ((unsigned)gj < (unsigned)NROWS) a = attn[(size_t)gi * NROWS + gj] * 256.f;
        if ((unsigned)(gj + 1) < (unsigned)NROWS) b = attn[(size_t)gi * NROWS + gj + 1] * 256.f;
      }
      buf[0][r * SSTRH + d] = h2u(__float22half2_rn(make_float2(a, b)));
    }
  }
  __syncthreads();

  int wv = tid >> 6, l = tid & 63;
  int rb = 1 + 6 * wv;
  int doff = 2 * l;
  __half2 CM0 = __float2half2_rn(1.f), CM1 = __float2half2_rn(1.f);
  if (edge) {
    float m0 = ((unsigned)(gj0 + 4 * l + 0) < (unsigned)NROWS) ? 1.f : 0.f;
    float m1 = ((unsigned)(gj0 + 4 * l + 1) < (unsigned)NROWS) ? 1.f : 0.f;
    float m2 = ((unsigned)(gj0 + 4 * l + 2) < (unsigned)NROWS) ? 1.f : 0.f;
    float m3 = ((unsigned)(gj0 + 4 * l + 3) < (unsigned)NROWS) ? 1.f : 0.f;
    CM0 = __float22half2_rn(make_float2(m0, m1));
    CM1 = __float22half2_rn(make_float2(m2, m3));
  }

  for (int p = 0; p < 10; ++p) {
    unsigned* src = buf[p & 1];
    unsigned* dst = buf[(p + 1) & 1];
    __half2 W10 = __float2half2_rn(w1p[3 * p]);
    __half2 W12 = __float2half2_rn(w1p[3 * p + 2]);
    __half2 WC  = __float2half2_rn(w1p[3 * p + 1] + w2p[3 * p + 1]);
    __half2 W20 = __float2half2_rn(w2p[3 * p]);
    __half2 W22 = __float2half2_rn(w2p[3 * p + 2]);
    __half2 AL  = __float2half2_rn(ap[p]);
    uint2 Vm = *(uint2*)&src[(rb - 1) * SSTRH + doff];
    uint2 Vc = *(uint2*)&src[rb * SSTRH + doff];
#pragma unroll
    for (int s = 0; s < 6; ++s) {
      int r = rb + s;
      uint2 Vp = *(uint2*)&src[(r + 1) * SSTRH + doff];
      unsigned Lm1 = (unsigned)__builtin_amdgcn_update_dpp(
          0, (int)Vc.y, 0x138, 0xF, 0xF, true);  // wave_shr1
      unsigned Hp1 = (unsigned)__builtin_amdgcn_update_dpp(
          0, (int)Vc.x, 0x130, 0xF, 0xF, true);  // wave_shl1
      unsigned SL0 = __builtin_amdgcn_alignbit(Vc.x, Lm1, 16);
      unsigned SR0 = __builtin_amdgcn_alignbit(Vc.y, Vc.x, 16);
      unsigned SR1 = __builtin_amdgcn_alignbit(Hp1, Vc.y, 16);
      __half2 o0 = __hmul2(WC, u2h(Vc.x));
      o0 = __hfma2(W10, u2h(SL0), o0);
      o0 = __hfma2(W12, u2h(SR0), o0);
      o0 = __hfma2(W20, u2h(Vm.x), o0);
      o0 = __hfma2(W22, u2h(Vp.x), o0);
      __half2 o1 = __hmul2(WC, u2h(Vc.y));
      o1 = __hfma2(W10, u2h(SR0), o1);
      o1 = __hfma2(W12, u2h(SR1), o1);
      o1 = __hfma2(W20, u2h(Vm.y), o1);
      o1 = __hfma2(W22, u2h(Vp.y), o1);
      // leaky relu = max(x, a*x), 0<a<1, via v_pk_max_f16
      {
        unsigned u0 = h2u(o0), ua0 = h2u(__hmul2(AL, o0)), r0;
        asm("v_pk_max_f16 %0, %1, %2" : "=v"(r0) : "v"(u0), "v"(ua0));
        o0 = u2h(r0);
        unsigned u1 = h2u(o1), ua1 = h2u(__hmul2(AL, o1)), r1;
        asm("v_pk_max_f16 %0, %1, %2" : "=v"(r1) : "v"(u1), "v"(ua1));
        o1 = u2h(r1);
      }
      if (edge) {
        o0 = __hmul2(o0, CM0);
        o1 = __hmul2(o1, CM1);
        if ((unsigned)(gi0 + r) >= (unsigned)NROWS) {
          o0 = __float2half2_rn(0.f);
          o1 = __float2half2_rn(0.f);
        }
      }
      uint2 res = {h2u(o0), h2u(o1)};
      *(uint2*)&dst[r * SSTRH + doff] = res;
      Vm = Vc; Vc = Vp;
    }
    __syncthreads();
  }

  // ---- epilogue: masked dot over interior rows [10,40), cols [10,246) ----
  const unsigned* fin = buf[0];
  int i = tid >> 4;
  int part = tid & 15;
  int gi = gi0 + 10 + i;
  float a0 = 0.f, a1 = 0.f, a2 = 0.f, a3 = 0.f;
  if (i < OHH && gi < NROWS) {
    for (int g = part; g < 59; g += 16) {
      int jc = 10 + 4 * g;
      int gj = gj0 + jc;
      if (gj + 3 < NROWS) {
        unsigned d0 = fin[(10 + i) * SSTRH + (jc >> 1)];
        unsigned d1 = fin[(10 + i) * SSTRH + (jc >> 1) + 1];
        __half2 h0 = u2h(d0), h1 = u2h(d1);
        float4 av = *(const float4*)(attn + (size_t)gi * NROWS + gj);
        const float4* op = (const float4*)opk;
        if (__low2float(h0) > 0.f)  { float4 o = op[gj + 0]; a0 += av.x * o.x; a1 += av.x * o.y; a2 += av.x * o.z; a3 += av.x * o.w; }
        if (__high2float(h0) > 0.f) { float4 o = op[gj + 1]; a0 += av.y * o.x; a1 += av.y * o.y; a2 += av.y * o.z; a3 += av.y * o.w; }
        if (__low2float(h1) > 0.f)  { float4 o = op[gj + 2]; a0 += av.z * o.x; a1 += av.z * o.y; a2 += av.z * o.z; a3 += av.z * o.w; }
        if (__high2float(h1) > 0.f) { float4 o = op[gj + 3]; a0 += av.w * o.x; a1 += av.w * o.y; a2 += av.w * o.z; a3 += av.w * o.w; }
      }
    }
  }
#pragma unroll
  for (int off = 1; off < 16; off <<= 1) {
    a0 += __shfl_xor(a0, off, 64);
    a1 += __shfl_xor(a1, off, 64);
    a2 += __shfl_xor(a2, off, 64);
    a3 += __shfl_xor(a3, off, 64);
  }
  if (part == 0 && i < OHH && gi < NROWS) {
    float4 r = {a0, a1, a2, a3};
    *(float4*)&partial[((size_t)bx * NROWS + gi) * 4] = r;
  }
}

// ---------------- kernel 4: reduce 18 partials + gcn + mlp head -----------
__global__ __launch_bounds__(64) void k_head(
    const float* __restrict__ partial, const float* __restrict__ gcn_w,
    const float* __restrict__ gcn_b, const float* __restrict__ gcn_a,
    const float* __restrict__ w1, const float* __restrict__ b1,
    const float* __restrict__ w2, const float* __restrict__ b2,
    float* __restrict__ out) {
  int row = blockIdx.x;
  int t = threadIdx.x;  // 64
  __shared__ float c4[4];
  __shared__ float gs[64];
  __shared__ float ms[32];
  {
    int c = t & 3, gg = t >> 2;
    float s = partial[((size_t)gg * NROWS + row) * 4 + c];
    if (gg < GX - 16)
      s += partial[((size_t)(gg + 16) * NROWS + row) * 4 + c];
#pragma unroll
    for (int off = 4; off < 64; off <<= 1) s += __shfl_xor(s, off, 64);
    if (t < 4) c4[t] = s;
  }
  __syncthreads();
  float g = gcn_b[t];
#pragma unroll
  for (int d = 0; d < 4; ++d) g += c4[d] * gcn_w[d * 64 + t];
  float ga = gcn_a[0];
  gs[t] = (g >= 0.f) ? g : ga * g;
  __syncthreads();
  if (t < 32) {
    float mm = b1[t];
#pragma unroll
    for (int i = 0; i < 64; ++i) mm += gs[i] * w1[i * 32 + t];
    ms[t] = fmaxf(mm, 0.f);
  }
  __syncthreads();
  if (t < 4) {
    float o = b2[t];
#pragma unroll
    for (int i = 0; i < 32; ++i) o += ms[i] * w2[i * 4 + t];
    out[row * 4 + t] = o;
  }
}

extern "C" void kernel_launch(void* const* d_in, const int* in_sizes, int n_in,
                              void* d_out, int out_size, void* d_ws, size_t ws_size,
                              hipStream_t stream) {
  (void)in_sizes; (void)n_in; (void)out_size; (void)ws_size;
  const float* inp    = (const float*)d_in[0];
  const float* emb_w  = (const float*)d_in[1];
  const float* emb_b  = (const float*)d_in[2];
  const float* q_w    = (const float*)d_in[3];
  const float* q_b    = (const float*)d_in[4];
  const float* k_w    = (const float*)d_in[5];
  const float* k_b    = (const float*)d_in[6];
  const float* conv_w1 = (const float*)d_in[7];
  const float* conv_w2 = (const float*)d_in[8];
  const float* conv_a  = (const float*)d_in[9];
  const float* gcn_w  = (const float*)d_in[10];
  const float* gcn_b  = (const float*)d_in[11];
  const float* gcn_a  = (const float*)d_in[12];
  const float* mlp_w1 = (const float*)d_in[13];
  const float* mlp_b1 = (const float*)d_in[14];
  const float* mlp_w2 = (const float*)d_in[15];
  const float* mlp_b2 = (const float*)d_in[16];
  float* out = (float*)d_out;

  const size_t NN = (size_t)NROWS * NROWS;
  float* A       = (float*)d_ws;                      // 4096^2 attn
  float* partial = A + NN;                            // GX * 4096 * 4
  float* qhf     = partial + (size_t)GX * NROWS * 4;  // fp16 Q, 512 KB
  float* khf     = qhf + (size_t)NROWS * HID / 2;     // fp16 K, 512 KB
  float* opk     = khf + (size_t)NROWS * HID / 2;

  k_embed<<<NROWS, 64, 0, stream>>>(inp, emb_w, emb_b, q_w, q_b, k_w, k_b,
                                    (__half*)qhf, (__half*)khf, opk);
  k_scores<<<NROWS / 16, 512, 0, stream>>>((const __half*)qhf,
                                           (const __half*)khf, A);
  k_conv3<<<dim3(GX, GY), 512, 0, stream>>>(A, partial, conv_w1, conv_w2,
                                            conv_a, opk);
  k_head<<<NROWS, 64, 0, stream>>>(partial, gcn_w, gcn_b, gcn_a, mlp_w1, mlp_b1,
                                   mlp_w2, mlp_b2, out);
}